// Round 14
// baseline (256.598 us; speedup 1.0000x reference)
//
#include <hip/hip_runtime.h>
#include <hip/hip_bf16.h>
#include <stdint.h>

#define NN 32
#define CC 64
#define TTOT 256
#define VV 25
#define NS 3
constexpr int TV  = TTOT * VV;            // 6400
constexpr int CTV = CC * TV;              // 409600
constexpr size_t PLANE = (size_t)NN * CTV; // 13107200

typedef unsigned short ushort_t;
using short8 = __attribute__((ext_vector_type(8))) short;
using f32x4  = __attribute__((ext_vector_type(4))) float;

static __device__ __forceinline__ ushort_t f2bf(float f) {
  __hip_bfloat16 h = __float2bfloat16(f);
  return reinterpret_cast<ushort_t&>(h);
}
static __device__ __forceinline__ float bf2f(ushort_t h) {
  union { uint32_t u; float f; } v; v.u = ((uint32_t)h) << 16;
  return v.f;
}
// element offset into a [row][128] bf16 tile, XOR-swizzled (byte ^= (row&7)<<4)
static __device__ __forceinline__ int SWZ(int row, int k) {
  return ((row << 7) + k) ^ ((row & 7) << 3);
}
static __device__ __forceinline__ f32x4 mfma16(short8 a, short8 b, f32x4 c) {
  return __builtin_amdgcn_mfma_f32_16x16x32_bf16(a, b, c, 0, 0, 0);
}
static __device__ __forceinline__ short8 negbf8(short8 x) {
  short8 r;
#pragma unroll
  for (int j = 0; j < 8; ++j) r[j] = x[j] ^ (short)0x8000;
  return r;
}

// ---------------------------------------------------------------------------
// K0: pre-fragment Wd (k'=2c+comp interleaved) and Wa/Wb (k=c planar) to bf16
// wfrag[i][ot(8)][m(4)][lane(64)][j(8)];  wab[i][mt(4)][ks(4)][lane(64)][j(8)]
// ---------------------------------------------------------------------------
__global__ __launch_bounds__(256) void k0_wfrag(
    const float* __restrict__ Wd, const float* __restrict__ Wa,
    const float* __restrict__ Wb, ushort_t* __restrict__ wfrag,
    ushort_t* __restrict__ wab)
{
  const int i = blockIdx.x;
  for (int e = threadIdx.x; e < 16384; e += 256) {
    int ot = e >> 11, m = (e >> 9) & 3, l = (e >> 3) & 63, j = e & 7;
    int r  = ot * 16 + (l & 15);
    int c = m * 16 + ((l >> 4) << 2) + (j >> 1), comp = j & 1;
    wfrag[(size_t)i * 16384 + e] = f2bf(Wd[(size_t)i * 16384 + r * 128 + comp * 64 + c]);
  }
  for (int e = threadIdx.x; e < 8192; e += 256) {
    int mt = e >> 11, ks = (e >> 9) & 3, l = (e >> 3) & 63, j = e & 7;
    int r  = mt * 16 + (l & 15);
    int kp = ks * 32 + ((l >> 4) << 3) + j;
    float v = (r < 32) ? Wa[((size_t)i * 32 + r) * 128 + kp]
                       : Wb[((size_t)i * 32 + (r - 32)) * 128 + kp];
    wab[(size_t)i * 8192 + e] = f2bf(v);
  }
}

// ---------------------------------------------------------------------------
// K1: per (n, tc) with 4 t's. Merged i-loop: conv for ALL 3 i (barrier-free)
// -> one barrier -> gram for all 3 i. 2 barriers total.
// Spart[3][32][64][25][25][2]. LDS 80KB -> 2 blocks/CU.
// ---------------------------------------------------------------------------
__global__ __launch_bounds__(256) void k1_spart(
    const float* __restrict__ xr, const float* __restrict__ xi,
    const ushort_t* __restrict__ wab, const float* __restrict__ ba,
    const float* __restrict__ bb, float* __restrict__ Spart)
{
  const int tc = blockIdx.x, n = blockIdx.y;
  const int tid = threadIdx.x, lane = tid & 63, wv = tid >> 6;
  const int r16 = lane & 15, gw = lane >> 4;
  __shared__ alignas(16) ushort_t zc[128 * 128];     // 32KB
  __shared__ alignas(16) ushort_t Ga[NS][32 * 128];  // 24KB
  __shared__ alignas(16) ushort_t Gb[NS][32 * 128];  // 24KB

  for (int e4 = tid; e4 < 128 * 25; e4 += 256) {
    int c = e4 / 25, q = e4 % 25;
    const float* src = (c < 64) ? xr : xi;
    float4 w = *(const float4*)&src[(size_t)n * CTV + (c & 63) * TV + tc * 100 + q * 4];
#pragma unroll
    for (int jj = 0; jj < 4; ++jj) {
      int g = q * 4 + jj, t = g / 25, v = g - t * 25;
      zc[SWZ(t * 32 + v, c)] = f2bf(((const float*)&w)[jj]);
    }
  }
  for (int e = tid; e < 28 * 128; e += 256) {  // zero-pad v=25..31
    int r7 = e >> 7, c = e & 127;
    int t = r7 / 7, vv = 25 + r7 % 7;
    zc[SWZ(t * 32 + vv, c)] = 0;
  }
  __syncthreads();

  // conv for all 3 i: wave wv = component (0=ar 1=ai 2=br 3=bi)
#pragma unroll 1
  for (int i = 0; i < NS; ++i) {
    short8 afr[4];
#pragma unroll
    for (int ks = 0; ks < 4; ++ks)
      afr[ks] = *(const short8*)&wab[((((size_t)i * 4 + wv) * 4 + ks) * 64 + lane) * 8];
    float bias[4];
#pragma unroll
    for (int j = 0; j < 4; ++j) {
      int row = wv * 16 + gw * 4 + j;
      bias[j] = (row < 32) ? ba[i * 32 + row] : bb[i * 32 + (row - 32)];
    }
    ushort_t* gbuf = (wv < 2) ? Ga[i] : Gb[i];
    const int half = (wv & 1) * 64;
    for (int nt = 0; nt < 8; ++nt) {
      f32x4 acc = {0.f, 0.f, 0.f, 0.f};
      const int brow = nt * 16 + r16;
#pragma unroll
      for (int ks = 0; ks < 4; ++ks) {
        short8 bfr = *(const short8*)&zc[SWZ(brow, ks * 32 + gw * 8)];
        acc = mfma16(afr[ks], bfr, acc);
      }
      int pos2 = nt * 16 + r16;
      int t = pos2 >> 5, v = pos2 & 31;
      int k0w = half + t * 16 + gw * 4;
      uint32_t w0 = (uint32_t)f2bf(acc[0] + bias[0]) | ((uint32_t)f2bf(acc[1] + bias[1]) << 16);
      uint32_t w1 = (uint32_t)f2bf(acc[2] + bias[2]) | ((uint32_t)f2bf(acc[3] + bias[3]) << 16);
      uint2 pk; pk.x = w0; pk.y = w1;
      *(uint2*)&gbuf[SWZ(v, k0w)] = pk;
    }
  }
  __syncthreads();

  // gram for all 3 i
  const int mu = wv >> 1, nv = wv & 1;
  const int urow = mu * 16 + r16;
  const int vrow = nv * 16 + r16;
#pragma unroll 1
  for (int i = 0; i < NS; ++i) {
    f32x4 Prr = {0.f,0.f,0.f,0.f}, Pii = {0.f,0.f,0.f,0.f};
    f32x4 Pri = {0.f,0.f,0.f,0.f}, Pir = {0.f,0.f,0.f,0.f};
#pragma unroll
    for (int ks = 0; ks < 2; ++ks) {
      int ko = ks * 32 + gw * 8;
      short8 arF = *(const short8*)&Ga[i][SWZ(urow, ko)];
      short8 aiF = *(const short8*)&Ga[i][SWZ(urow, 64 + ko)];
      short8 brF = *(const short8*)&Gb[i][SWZ(vrow, ko)];
      short8 biF = *(const short8*)&Gb[i][SWZ(vrow, 64 + ko)];
      Prr = mfma16(arF, brF, Prr);
      Pii = mfma16(aiF, biF, Pii);
      Pri = mfma16(arF, biF, Pri);
      Pir = mfma16(aiF, brF, Pir);
    }
#pragma unroll
    for (int j = 0; j < 4; ++j) {
      int u = mu * 16 + gw * 4 + j;
      int v = nv * 16 + r16;
      if (u < VV && v < VV) {
        size_t idx = ((((size_t)i * NN + n) * 64 + tc) * 625 + u * 25 + v) * 2;
        Spart[idx]     = Prr[j] - Pii[j];
        Spart[idx + 1] = Pri[j] + Pir[j];
      }
    }
  }
}

// ---------------------------------------------------------------------------
// K2: reduce Spart over tc, /4096, complex softmax over u, + (A+PA),
//     emit packed bf16 S-fragments. sfrag[i][n][m(2)][nt(2)][lane(64)][j(8)]
// ---------------------------------------------------------------------------
__global__ __launch_bounds__(256) void k2_softmax(
    const float* __restrict__ Spart, const float* __restrict__ Aw,
    const float* __restrict__ PA, ushort_t* __restrict__ sfrag)
{
  const int i = blockIdx.x, n = blockIdx.y, tid = threadIdx.x;
  __shared__ float ez[625 * 2];
  __shared__ float den[25 * 2];
  for (int e = tid; e < 625; e += 256) {
    float sr = 0.f, si = 0.f;
    const float* p = Spart + (((size_t)i * NN + n) * 64 * 625 + e) * 2;
    for (int tcb = 0; tcb < 64; ++tcb) { sr += p[0]; si += p[1]; p += 625 * 2; }
    sr *= (1.f / 4096.f); si *= (1.f / 4096.f);
    float m = expf(sr);
    ez[e * 2] = m * cosf(si);
    ez[e * 2 + 1] = m * sinf(si);
  }
  __syncthreads();
  if (tid < 25) {
    float dr = 0.f, di = 0.f;
    for (int u = 0; u < 25; ++u) { dr += ez[(u * 25 + tid) * 2]; di += ez[(u * 25 + tid) * 2 + 1]; }
    float inv = 1.f / (dr * dr + di * di);
    den[tid * 2] = dr * inv; den[tid * 2 + 1] = -di * inv;
  }
  __syncthreads();
  for (int e = tid; e < 625; e += 256) {
    int v = e % 25;
    float er = ez[e * 2], ei = ez[e * 2 + 1];
    float dr = den[v * 2], di = den[v * 2 + 1];
    float outr = er * dr - ei * di + Aw[i * 625 + e] + PA[i * 625 + e];
    float outi = er * di + ei * dr;
    ez[e * 2] = outr; ez[e * 2 + 1] = outi;
  }
  __syncthreads();
  for (int e = tid; e < 256; e += 256) {
    int l = e & 63, nt = (e >> 6) & 1, m = e >> 7;
    int u0 = (l >> 4) << 3, v = nt * 16 + (l & 15);
    short8 pk;
#pragma unroll
    for (int j = 0; j < 8; ++j) {
      int u = u0 + j;
      float val = 0.f;
      if (u < VV && v < VV)
        val = (m == 0) ? ez[(u * 25 + v) * 2] : ez[(u * 25 + v) * 2 + 1];
      pk[j] = (short)f2bf(val);
    }
    *(short8*)&sfrag[((size_t)(i * NN + n) * 256 + e) * 8] = pk;
  }
}

// ---------------------------------------------------------------------------
// K3: small-LDS form. Block = (tq2, n): 2 t's, 256 thr / 4 waves.
// Wave wv = (tl = wv>>1, h = wv&1): t = tq2*2+tl, output half h (4 ot-tiles).
// LDS = xs 16KB + wbuf 32KB (re-staged per i) + stats 2KB = 50KB -> 3 blk/CU.
// z in registers (m-streamed C-frag -> B-frag pack, bp transient 8 VGPR).
// xs u-index swizzled (u ^= (c&3)<<3) to cut phase-A read conflicts to <=4-way.
// ---------------------------------------------------------------------------
__global__ __launch_bounds__(256) void k3_y(
    const float* __restrict__ xr, const float* __restrict__ xi,
    const ushort_t* __restrict__ sfrag, const ushort_t* __restrict__ wfrag,
    const float* __restrict__ bd, float* __restrict__ out,
    float* __restrict__ bnpart)
{
  const int tq2 = blockIdx.x, n = blockIdx.y;
  const int tid = threadIdx.x, lane = tid & 63, wv = tid >> 6;
  const int r16 = lane & 15, gw = lane >> 4;
  const int tl = wv >> 1, h = wv & 1;
  __shared__ alignas(16) ushort_t xs[2][4096];   // [t][c*32 + (u ^ ((c&3)<<3))]
  __shared__ alignas(16) ushort_t wbuf[16384];   // one i's wfrag (32KB)
  __shared__ float stats[4][64][2];              // 2KB

  // stage x for 2 t's: coalesced float2 loads, swizzled scalar LDS writes
  for (int e2 = tid; e2 < 128 * 25; e2 += 256) {
    int c = e2 / 25, q = e2 % 25;
    const float* src = (c < 64) ? xr : xi;
    float2 w = *(const float2*)&src[(size_t)n * CTV + (size_t)(c & 63) * TV + tq2 * 50 + q * 2];
    int g0 = q * 2, g1 = g0 + 1;
    int t0 = g0 / 25, u0 = g0 - t0 * 25;
    int t1 = g1 / 25, u1 = g1 - t1 * 25;
    int sw = (c & 3) << 3;
    xs[t0][c * 32 + (u0 ^ sw)] = f2bf(w.x);
    xs[t1][c * 32 + (u1 ^ sw)] = f2bf(w.y);
  }
  for (int e = tid; e < 128 * 14; e += 256) {    // pad u=25..31 both t
    int c = e / 14, r = e % 14;
    int t = r / 7, u = 25 + r % 7;
    xs[t][c * 32 + (u ^ ((c & 3) << 3))] = 0;
  }

  f32x4 acc[4][2];
#pragma unroll
  for (int a = 0; a < 4; ++a) { acc[a][0] = {0.f,0.f,0.f,0.f}; acc[a][1] = {0.f,0.f,0.f,0.f}; }

#pragma unroll 1
  for (int i = 0; i < NS; ++i) {
    __syncthreads();  // WAR: prev compute done with wbuf (i=0: xs published too)

    // stage W[i]: 8 coalesced b128 global loads -> LDS (L2-hot)
    short8 tmp[8];
#pragma unroll
    for (int q = 0; q < 8; ++q)
      tmp[q] = *(const short8*)&wfrag[(size_t)i * 16384 + (size_t)(q * 256 + tid) * 8];
    // S fragments for this i (4 coalesced b128, L2-hot)
    const ushort_t* sb = sfrag + (size_t)(i * NN + n) * 2048;
    short8 sf[2][2];
#pragma unroll
    for (int m = 0; m < 2; ++m)
#pragma unroll
      for (int nt = 0; nt < 2; ++nt)
        sf[m][nt] = *(const short8*)&sb[((m * 2 + nt) * 64 + lane) * 8];
#pragma unroll
    for (int q = 0; q < 8; ++q)
      *(short8*)&wbuf[(q * 256 + tid) * 8] = tmp[q];
    __syncthreads();  // wbuf ready

    short8 snI[2];
#pragma unroll
    for (int nt = 0; nt < 2; ++nt) snI[nt] = negbf8(sf[1][nt]);

    // m-streamed: phase A for tile m (bp transient), then its phase-B MFMAs
#pragma unroll
    for (int m = 0; m < 4; ++m) {
      int cr = m * 16 + r16;
      int ko = (gw * 8) ^ ((r16 & 3) << 3);
      short8 axr_ = *(const short8*)&xs[tl][cr * 32 + ko];
      short8 axi_ = *(const short8*)&xs[tl][(64 + cr) * 32 + ko];
      short8 bp[2];
#pragma unroll
      for (int nt = 0; nt < 2; ++nt) {
        f32x4 zr = {0.f,0.f,0.f,0.f}, zi = {0.f,0.f,0.f,0.f};
        zr = mfma16(axr_, sf[0][nt], zr);
        zr = mfma16(axi_, snI[nt], zr);
        zi = mfma16(axr_, sf[1][nt], zi);
        zi = mfma16(axi_, sf[0][nt], zi);
        short8 pk;
#pragma unroll
        for (int j = 0; j < 4; ++j) {
          pk[2 * j]     = (short)f2bf(zr[j]);
          pk[2 * j + 1] = (short)f2bf(zi[j]);
        }
        bp[nt] = pk;
      }
#pragma unroll
      for (int otl = 0; otl < 4; ++otl) {
        int ot = h * 4 + otl;
        short8 a = *(const short8*)&wbuf[(size_t)((ot * 4 + m) * 64 + lane) * 8];
        acc[otl][0] = mfma16(a, bp[0], acc[otl][0]);
        acc[otl][1] = mfma16(a, bp[1], acc[otl][1]);
      }
    }
  }

  // epilogue: bias, write y (t = tq2*2+tl, rows h*64+lrow), BN partials
  const int t = tq2 * 2 + tl;
#pragma unroll
  for (int otl = 0; otl < 4; ++otl) {
#pragma unroll
    for (int j = 0; j < 4; ++j) {
      int lrow = otl * 16 + gw * 4 + j;
      int row = h * 64 + lrow;
      float bias = bd[row] + bd[128 + row] + bd[256 + row];
      float s = 0.f, q = 0.f;
#pragma unroll
      for (int nt = 0; nt < 2; ++nt) {
        int v = nt * 16 + r16;
        float val = acc[otl][nt][j] + bias;
        if (v < VV) {
          out[(size_t)(row >> 6) * PLANE + (size_t)n * CTV + (row & 63) * TV + t * VV + v] = val;
          s += val; q += val * val;
        }
      }
#pragma unroll
      for (int d = 1; d < 16; d <<= 1) { s += __shfl_xor(s, d); q += __shfl_xor(q, d); }
      if (r16 == 0) { stats[wv][lrow][0] = s; stats[wv][lrow][1] = q; }
    }
  }
  __syncthreads();
  if (tid < 128) {
    int hh = tid >> 6, lr = tid & 63;   // row tid = hh*64 + lr
    float s = stats[hh][lr][0] + stats[2 + hh][lr][0];   // tl=0 + tl=1
    float q = stats[hh][lr][1] + stats[2 + hh][lr][1];
    size_t b = (size_t)n * 128 + tq2;
    bnpart[(b * 128 + tid) * 2]     = s;
    bnpart[(b * 128 + tid) * 2 + 1] = q;
  }
}

// ---------------------------------------------------------------------------
// K4: reduce bnpart (4096 partials) -> per-channel coeff
// ---------------------------------------------------------------------------
__global__ __launch_bounds__(256) void k4_stats(
    const float* __restrict__ bnpart, const float* __restrict__ bnw,
    const float* __restrict__ bnb, float* __restrict__ coeff)
{
  const int o = blockIdx.x, tid = threadIdx.x;
  float sr = 0.f, qr = 0.f, si = 0.f, qi = 0.f;
  for (int b = tid; b < 4096; b += 256) {
    const float* p = bnpart + ((size_t)b * 128 + o) * 2;
    sr += p[0]; qr += p[1];
    const float* p2 = bnpart + ((size_t)b * 128 + 64 + o) * 2;
    si += p2[0]; qi += p2[1];
  }
#pragma unroll
  for (int d = 1; d < 64; d <<= 1) {
    sr += __shfl_xor(sr, d); qr += __shfl_xor(qr, d);
    si += __shfl_xor(si, d); qi += __shfl_xor(qi, d);
  }
  __shared__ float red[4][4];
  int lane = tid & 63, wv = tid >> 6;
  if (lane == 0) { red[wv][0] = sr; red[wv][1] = qr; red[wv][2] = si; red[wv][3] = qi; }
  __syncthreads();
  if (tid == 0) {
    sr = red[0][0] + red[1][0] + red[2][0] + red[3][0];
    qr = red[0][1] + red[1][1] + red[2][1] + red[3][1];
    si = red[0][2] + red[1][2] + red[2][2] + red[3][2];
    qi = red[0][3] + red[1][3] + red[2][3] + red[3][3];
    const float invM = 1.f / (float)((size_t)NN * TTOT * VV);
    float mur = sr * invM, mui = si * invM;
    float var = (qr + qi) * invM - mur * mur - mui * mui;
    float inv = rsqrtf(var + 1e-5f);
    coeff[o * 4 + 0] = mur; coeff[o * 4 + 1] = mui;
    coeff[o * 4 + 2] = inv * bnw[o]; coeff[o * 4 + 3] = bnb[o];
  }
}

// ---------------------------------------------------------------------------
// K5: yn = (y - mu)*scale + shift + x  (in-place on d_out, vectorized)
// ---------------------------------------------------------------------------
__global__ __launch_bounds__(256) void k5_norm(
    const float* __restrict__ xr, const float* __restrict__ xi,
    const float* __restrict__ coeff, float* __restrict__ out)
{
  size_t idx0 = ((size_t)blockIdx.x * 256 + threadIdx.x) * 4;
  size_t stride = (size_t)gridDim.x * 256 * 4;
  for (size_t e = idx0; e < PLANE; e += stride) {
    int o = (int)((e / TV) & 63);
    float4 cf = *(const float4*)&coeff[o * 4];
    float4 yr = *(float4*)&out[e];
    float4 yi = *(float4*)&out[PLANE + e];
    float4 vr = *(const float4*)&xr[e];
    float4 vi = *(const float4*)&xi[e];
    yr.x = (yr.x - cf.x) * cf.z + cf.w + vr.x;
    yr.y = (yr.y - cf.x) * cf.z + cf.w + vr.y;
    yr.z = (yr.z - cf.x) * cf.z + cf.w + vr.z;
    yr.w = (yr.w - cf.x) * cf.z + cf.w + vr.w;
    yi.x = (yi.x - cf.y) * cf.z + vi.x;
    yi.y = (yi.y - cf.y) * cf.z + vi.y;
    yi.z = (yi.z - cf.y) * cf.z + vi.z;
    yi.w = (yi.w - cf.y) * cf.z + vi.w;
    *(float4*)&out[e] = yr;
    *(float4*)&out[PLANE + e] = yi;
  }
}

// ---------------------------------------------------------------------------
extern "C" void kernel_launch(void* const* d_in, const int* in_sizes, int n_in,
                              void* d_out, int out_size, void* d_ws, size_t ws_size,
                              hipStream_t stream) {
  const float* xr  = (const float*)d_in[0];
  const float* xi  = (const float*)d_in[1];
  const float* Aw  = (const float*)d_in[2];
  const float* PA  = (const float*)d_in[3];
  const float* Wa  = (const float*)d_in[4];
  const float* ba  = (const float*)d_in[5];
  const float* Wb  = (const float*)d_in[6];
  const float* bb  = (const float*)d_in[7];
  const float* Wd  = (const float*)d_in[8];
  const float* bd  = (const float*)d_in[9];
  const float* bnw = (const float*)d_in[10];
  const float* bnb = (const float*)d_in[11];
  float* out = (float*)d_out;
  float* ws = (float*)d_ws;

  // ws layout (floats). bnpart aliases Spart (Spart dead after k2).
  float*    Spart  = ws;                         // 7,680,000 floats
  float*    bnpart = ws;                         // 1,048,576 floats (alias)
  ushort_t* sfrag  = (ushort_t*)(ws + 7680000);  // 196,608 ushorts
  ushort_t* wfrag  = (ushort_t*)(ws + 7778304);  // 49,152 ushorts
  ushort_t* wab    = (ushort_t*)(ws + 7802880);  // 24,576 ushorts
  float*    coeff  = ws + 7815168;               // 256 floats
  // total ≈ 31.3 MB

  k0_wfrag<<<NS, 256, 0, stream>>>(Wd, Wa, Wb, wfrag, wab);
  k1_spart<<<dim3(64, NN), 256, 0, stream>>>(xr, xi, wab, ba, bb, Spart);
  k2_softmax<<<dim3(NS, NN), 256, 0, stream>>>(Spart, Aw, PA, sfrag);
  k3_y<<<dim3(128, NN), 256, 0, stream>>>(xr, xi, sfrag, wfrag, bd, out, bnpart);
  k4_stats<<<64, 256, 0, stream>>>(bnpart, bnw, bnb, coeff);
  k5_norm<<<6400, 256, 0, stream>>>(xr, xi, coeff, out);
}

// Round 15
// 254.616 us; speedup vs baseline: 1.0078x; 1.0078x over previous
//
#include <hip/hip_runtime.h>
#include <hip/hip_bf16.h>
#include <stdint.h>

#define NN 32
#define CC 64
#define TTOT 256
#define VV 25
#define NS 3
constexpr int TV  = TTOT * VV;            // 6400
constexpr int CTV = CC * TV;              // 409600
constexpr size_t PLANE = (size_t)NN * CTV; // 13107200

typedef unsigned short ushort_t;
using short8 = __attribute__((ext_vector_type(8))) short;
using f32x4  = __attribute__((ext_vector_type(4))) float;

static __device__ __forceinline__ ushort_t f2bf(float f) {
  __hip_bfloat16 h = __float2bfloat16(f);
  return reinterpret_cast<ushort_t&>(h);
}
static __device__ __forceinline__ float bf2f(ushort_t h) {
  union { uint32_t u; float f; } v; v.u = ((uint32_t)h) << 16;
  return v.f;
}
// element offset into a [row][128] bf16 tile, XOR-swizzled (byte ^= (row&7)<<4)
static __device__ __forceinline__ int SWZ(int row, int k) {
  return ((row << 7) + k) ^ ((row & 7) << 3);
}
static __device__ __forceinline__ f32x4 mfma16(short8 a, short8 b, f32x4 c) {
  return __builtin_amdgcn_mfma_f32_16x16x32_bf16(a, b, c, 0, 0, 0);
}
static __device__ __forceinline__ short8 negbf8(short8 x) {
  short8 r;
#pragma unroll
  for (int j = 0; j < 8; ++j) r[j] = x[j] ^ (short)0x8000;
  return r;
}

// ---------------------------------------------------------------------------
// K0: pre-fragment Wd (k'=2c+comp interleaved) and Wa/Wb (k=c planar) to bf16
// wfrag[i][ot(8)][m(4)][lane(64)][j(8)];  wab[i][mt(4)][ks(4)][lane(64)][j(8)]
// ---------------------------------------------------------------------------
__global__ __launch_bounds__(256) void k0_wfrag(
    const float* __restrict__ Wd, const float* __restrict__ Wa,
    const float* __restrict__ Wb, ushort_t* __restrict__ wfrag,
    ushort_t* __restrict__ wab)
{
  const int i = blockIdx.x;
  for (int e = threadIdx.x; e < 16384; e += 256) {
    int ot = e >> 11, m = (e >> 9) & 3, l = (e >> 3) & 63, j = e & 7;
    int r  = ot * 16 + (l & 15);
    int c = m * 16 + ((l >> 4) << 2) + (j >> 1), comp = j & 1;
    wfrag[(size_t)i * 16384 + e] = f2bf(Wd[(size_t)i * 16384 + r * 128 + comp * 64 + c]);
  }
  for (int e = threadIdx.x; e < 8192; e += 256) {
    int mt = e >> 11, ks = (e >> 9) & 3, l = (e >> 3) & 63, j = e & 7;
    int r  = mt * 16 + (l & 15);
    int kp = ks * 32 + ((l >> 4) << 3) + j;
    float v = (r < 32) ? Wa[((size_t)i * 32 + r) * 128 + kp]
                       : Wb[((size_t)i * 32 + (r - 32)) * 128 + kp];
    wab[(size_t)i * 8192 + e] = f2bf(v);
  }
}

// ---------------------------------------------------------------------------
// K1: per (n, tc) with 4 t's. Merged i-loop: conv for ALL 3 i (barrier-free)
// -> one barrier -> gram for all 3 i. 2 barriers total. LDS 80KB.
// ---------------------------------------------------------------------------
__global__ __launch_bounds__(256) void k1_spart(
    const float* __restrict__ xr, const float* __restrict__ xi,
    const ushort_t* __restrict__ wab, const float* __restrict__ ba,
    const float* __restrict__ bb, float* __restrict__ Spart)
{
  const int tc = blockIdx.x, n = blockIdx.y;
  const int tid = threadIdx.x, lane = tid & 63, wv = tid >> 6;
  const int r16 = lane & 15, gw = lane >> 4;
  __shared__ alignas(16) ushort_t zc[128 * 128];
  __shared__ alignas(16) ushort_t Ga[NS][32 * 128];
  __shared__ alignas(16) ushort_t Gb[NS][32 * 128];

  for (int e4 = tid; e4 < 128 * 25; e4 += 256) {
    int c = e4 / 25, q = e4 % 25;
    const float* src = (c < 64) ? xr : xi;
    float4 w = *(const float4*)&src[(size_t)n * CTV + (c & 63) * TV + tc * 100 + q * 4];
#pragma unroll
    for (int jj = 0; jj < 4; ++jj) {
      int g = q * 4 + jj, t = g / 25, v = g - t * 25;
      zc[SWZ(t * 32 + v, c)] = f2bf(((const float*)&w)[jj]);
    }
  }
  for (int e = tid; e < 28 * 128; e += 256) {
    int r7 = e >> 7, c = e & 127;
    int t = r7 / 7, vv = 25 + r7 % 7;
    zc[SWZ(t * 32 + vv, c)] = 0;
  }
  __syncthreads();

#pragma unroll 1
  for (int i = 0; i < NS; ++i) {
    short8 afr[4];
#pragma unroll
    for (int ks = 0; ks < 4; ++ks)
      afr[ks] = *(const short8*)&wab[((((size_t)i * 4 + wv) * 4 + ks) * 64 + lane) * 8];
    float bias[4];
#pragma unroll
    for (int j = 0; j < 4; ++j) {
      int row = wv * 16 + gw * 4 + j;
      bias[j] = (row < 32) ? ba[i * 32 + row] : bb[i * 32 + (row - 32)];
    }
    ushort_t* gbuf = (wv < 2) ? Ga[i] : Gb[i];
    const int half = (wv & 1) * 64;
    for (int nt = 0; nt < 8; ++nt) {
      f32x4 acc = {0.f, 0.f, 0.f, 0.f};
      const int brow = nt * 16 + r16;
#pragma unroll
      for (int ks = 0; ks < 4; ++ks) {
        short8 bfr = *(const short8*)&zc[SWZ(brow, ks * 32 + gw * 8)];
        acc = mfma16(afr[ks], bfr, acc);
      }
      int pos2 = nt * 16 + r16;
      int t = pos2 >> 5, v = pos2 & 31;
      int k0w = half + t * 16 + gw * 4;
      uint32_t w0 = (uint32_t)f2bf(acc[0] + bias[0]) | ((uint32_t)f2bf(acc[1] + bias[1]) << 16);
      uint32_t w1 = (uint32_t)f2bf(acc[2] + bias[2]) | ((uint32_t)f2bf(acc[3] + bias[3]) << 16);
      uint2 pk; pk.x = w0; pk.y = w1;
      *(uint2*)&gbuf[SWZ(v, k0w)] = pk;
    }
  }
  __syncthreads();

  const int mu = wv >> 1, nv = wv & 1;
  const int urow = mu * 16 + r16;
  const int vrow = nv * 16 + r16;
#pragma unroll 1
  for (int i = 0; i < NS; ++i) {
    f32x4 Prr = {0.f,0.f,0.f,0.f}, Pii = {0.f,0.f,0.f,0.f};
    f32x4 Pri = {0.f,0.f,0.f,0.f}, Pir = {0.f,0.f,0.f,0.f};
#pragma unroll
    for (int ks = 0; ks < 2; ++ks) {
      int ko = ks * 32 + gw * 8;
      short8 arF = *(const short8*)&Ga[i][SWZ(urow, ko)];
      short8 aiF = *(const short8*)&Ga[i][SWZ(urow, 64 + ko)];
      short8 brF = *(const short8*)&Gb[i][SWZ(vrow, ko)];
      short8 biF = *(const short8*)&Gb[i][SWZ(vrow, 64 + ko)];
      Prr = mfma16(arF, brF, Prr);
      Pii = mfma16(aiF, biF, Pii);
      Pri = mfma16(arF, biF, Pri);
      Pir = mfma16(aiF, brF, Pir);
    }
#pragma unroll
    for (int j = 0; j < 4; ++j) {
      int u = mu * 16 + gw * 4 + j;
      int v = nv * 16 + r16;
      if (u < VV && v < VV) {
        size_t idx = ((((size_t)i * NN + n) * 64 + tc) * 625 + u * 25 + v) * 2;
        Spart[idx]     = Prr[j] - Pii[j];
        Spart[idx + 1] = Pri[j] + Pir[j];
      }
    }
  }
}

// ---------------------------------------------------------------------------
// K2: softmax + pack bf16 S-fragments. sfrag[i][n][m(2)][nt(2)][lane(64)][j(8)]
// ---------------------------------------------------------------------------
__global__ __launch_bounds__(256) void k2_softmax(
    const float* __restrict__ Spart, const float* __restrict__ Aw,
    const float* __restrict__ PA, ushort_t* __restrict__ sfrag)
{
  const int i = blockIdx.x, n = blockIdx.y, tid = threadIdx.x;
  __shared__ float ez[625 * 2];
  __shared__ float den[25 * 2];
  for (int e = tid; e < 625; e += 256) {
    float sr = 0.f, si = 0.f;
    const float* p = Spart + (((size_t)i * NN + n) * 64 * 625 + e) * 2;
    for (int tcb = 0; tcb < 64; ++tcb) { sr += p[0]; si += p[1]; p += 625 * 2; }
    sr *= (1.f / 4096.f); si *= (1.f / 4096.f);
    float m = expf(sr);
    ez[e * 2] = m * cosf(si);
    ez[e * 2 + 1] = m * sinf(si);
  }
  __syncthreads();
  if (tid < 25) {
    float dr = 0.f, di = 0.f;
    for (int u = 0; u < 25; ++u) { dr += ez[(u * 25 + tid) * 2]; di += ez[(u * 25 + tid) * 2 + 1]; }
    float inv = 1.f / (dr * dr + di * di);
    den[tid * 2] = dr * inv; den[tid * 2 + 1] = -di * inv;
  }
  __syncthreads();
  for (int e = tid; e < 625; e += 256) {
    int v = e % 25;
    float er = ez[e * 2], ei = ez[e * 2 + 1];
    float dr = den[v * 2], di = den[v * 2 + 1];
    float outr = er * dr - ei * di + Aw[i * 625 + e] + PA[i * 625 + e];
    float outi = er * di + ei * dr;
    ez[e * 2] = outr; ez[e * 2 + 1] = outi;
  }
  __syncthreads();
  for (int e = tid; e < 256; e += 256) {
    int l = e & 63, nt = (e >> 6) & 1, m = e >> 7;
    int u0 = (l >> 4) << 3, v = nt * 16 + (l & 15);
    short8 pk;
#pragma unroll
    for (int j = 0; j < 8; ++j) {
      int u = u0 + j;
      float val = 0.f;
      if (u < VV && v < VV)
        val = (m == 0) ? ez[(u * 25 + v) * 2] : ez[(u * 25 + v) * 2 + 1];
      pk[j] = (short)f2bf(val);
    }
    *(short8*)&sfrag[((size_t)(i * NN + n) * 256 + e) * 8] = pk;
  }
}

// ---------------------------------------------------------------------------
// K3: block = (tq4, h, n): 4 t's, output half h. 256 thr / 4 waves, wave = t.
// LDS 50KB -> 3 blocks/CU (12 waves/CU) AND weights staged ONCE per block
// (48KB = h-half of all 3 i's) with a barrier-free 3-i loop (R13 schedule).
// x staged at stride-40 rows (2-way banks = free); x-frags hoisted to regs,
// then the x region is overwritten by the weight stage. acc = 32 VGPR.
// ---------------------------------------------------------------------------
__global__ __launch_bounds__(256) void k3_y(
    const float* __restrict__ xr, const float* __restrict__ xi,
    const ushort_t* __restrict__ sfrag, const ushort_t* __restrict__ wfrag,
    const float* __restrict__ bd, float* __restrict__ out,
    float* __restrict__ bnpart)
{
  const int tq4 = blockIdx.x >> 1, h = blockIdx.x & 1, n = blockIdx.y;
  const int tid = threadIdx.x, lane = tid & 63, wv = tid >> 6;
  const int r16 = lane & 15, gw = lane >> 4;
  __shared__ alignas(16) ushort_t smem[24576]; // 48KB: xs (20KB) then weights
  __shared__ float stats[4][64][2];            // 2KB

  // stage x for 4 t's: xs[t][c][u] with 40-ushort row stride (80B, 2-way banks)
  for (int e4 = tid; e4 < 128 * 25; e4 += 256) {
    int c = e4 / 25, q = e4 % 25;
    const float* src = (c < 64) ? xr : xi;
    float4 w = *(const float4*)&src[(size_t)n * CTV + (size_t)(c & 63) * TV + tq4 * 100 + q * 4];
#pragma unroll
    for (int jj = 0; jj < 4; ++jj) {
      int g = q * 4 + jj, t = g / 25, u = g - t * 25;
      smem[t * 5120 + c * 40 + u] = f2bf(((const float*)&w)[jj]);
    }
  }
  for (int e = tid; e < 128 * 28; e += 256) { // pad u=25..31, all 4 t
    int c = e / 28, r = e % 28;
    int t = r / 7, u = 25 + r % 7;
    smem[t * 5120 + c * 40 + u] = 0;
  }
  __syncthreads();

  // hoist x A-frags for wave's t (= wv): conflict-light b128 reads
  short8 axr[4], axi[4];
#pragma unroll
  for (int tile = 0; tile < 4; ++tile) {
    int cr = tile * 16 + r16;
    axr[tile] = *(const short8*)&smem[wv * 5120 + cr * 40 + gw * 8];
    axi[tile] = *(const short8*)&smem[wv * 5120 + (64 + cr) * 40 + gw * 8];
  }
  __syncthreads(); // xs dead; smem becomes weight store

  // stage h-half of all 3 i's weights: 12 coalesced b128/thread, batched 6+6
  {
    short8 tmp[6];
#pragma unroll
    for (int b = 0; b < 2; ++b) {
#pragma unroll
      for (int q = 0; q < 6; ++q) {
        int e = (b * 6 + q) * 256 + tid;
        int i = e >> 10, local = e & 1023;
        tmp[q] = *(const short8*)&wfrag[(size_t)i * 16384 + h * 8192 + (size_t)local * 8];
      }
#pragma unroll
      for (int q = 0; q < 6; ++q) {
        int e = (b * 6 + q) * 256 + tid;
        *(short8*)&smem[(size_t)e * 8] = tmp[q];
      }
    }
  }
  __syncthreads(); // weights ready; 3-i loop below is barrier-free

  f32x4 acc[4][2];
#pragma unroll
  for (int a = 0; a < 4; ++a) { acc[a][0] = {0.f,0.f,0.f,0.f}; acc[a][1] = {0.f,0.f,0.f,0.f}; }

  auto load_sf = [&](int i, short8 sf[2][2]) {
    const ushort_t* sb = sfrag + (size_t)(i * NN + n) * 2048;
#pragma unroll
    for (int m = 0; m < 2; ++m)
#pragma unroll
      for (int nt = 0; nt < 2; ++nt)
        sf[m][nt] = *(const short8*)&sb[((m * 2 + nt) * 64 + lane) * 8];
  };
  auto compute_i = [&](int i, short8 sf[2][2]) {
    short8 snI[2];
#pragma unroll
    for (int nt = 0; nt < 2; ++nt) snI[nt] = negbf8(sf[1][nt]);
    short8 bp[4][2];
#pragma unroll
    for (int tile = 0; tile < 4; ++tile) {
#pragma unroll
      for (int nt = 0; nt < 2; ++nt) {
        f32x4 zr = {0.f,0.f,0.f,0.f}, zi = {0.f,0.f,0.f,0.f};
        zr = mfma16(axr[tile], sf[0][nt], zr);
        zr = mfma16(axi[tile], snI[nt], zr);
        zi = mfma16(axr[tile], sf[1][nt], zi);
        zi = mfma16(axi[tile], sf[0][nt], zi);
        short8 pk;
#pragma unroll
        for (int j = 0; j < 4; ++j) {
          pk[2 * j]     = (short)f2bf(zr[j]);
          pk[2 * j + 1] = (short)f2bf(zi[j]);
        }
        bp[tile][nt] = pk;
      }
    }
    __builtin_amdgcn_s_setprio(1);
#pragma unroll
    for (int otl = 0; otl < 4; ++otl) {
#pragma unroll
      for (int m = 0; m < 4; ++m) {
        short8 a = *(const short8*)&smem[(size_t)i * 8192 + (size_t)((otl * 4 + m) * 64 + lane) * 8];
        acc[otl][0] = mfma16(a, bp[m][0], acc[otl][0]);
        acc[otl][1] = mfma16(a, bp[m][1], acc[otl][1]);
      }
    }
    __builtin_amdgcn_s_setprio(0);
  };

  // software-pipelined sfrag
  short8 sfA[2][2], sfB[2][2];
  load_sf(0, sfA);
  load_sf(1, sfB);
  compute_i(0, sfA);
  load_sf(2, sfA);
  compute_i(1, sfB);
  compute_i(2, sfA);

  // epilogue: bias, write y (t = tq4*4+wv, rows h*64+lrow), BN partials
  const int t = tq4 * 4 + wv;
#pragma unroll
  for (int otl = 0; otl < 4; ++otl) {
#pragma unroll
    for (int j = 0; j < 4; ++j) {
      int lrow = otl * 16 + gw * 4 + j;      // 0..63 within half
      int row = h * 64 + lrow;               // global row
      float bias = bd[row] + bd[128 + row] + bd[256 + row];
      float s = 0.f, q = 0.f;
#pragma unroll
      for (int nt = 0; nt < 2; ++nt) {
        int v = nt * 16 + r16;
        float val = acc[otl][nt][j] + bias;
        if (v < VV) {
          out[(size_t)h * PLANE + (size_t)n * CTV + (row & 63) * TV + t * VV + v] = val;
          s += val; q += val * val;
        }
      }
#pragma unroll
      for (int d = 1; d < 16; d <<= 1) { s += __shfl_xor(s, d); q += __shfl_xor(q, d); }
      if (r16 == 0) { stats[wv][lrow][0] = s; stats[wv][lrow][1] = q; }
    }
  }
  __syncthreads();
  if (tid < 64) {
    float s = stats[0][tid][0] + stats[1][tid][0] + stats[2][tid][0] + stats[3][tid][0];
    float q = stats[0][tid][1] + stats[1][tid][1] + stats[2][tid][1] + stats[3][tid][1];
    size_t b = (size_t)n * 64 + tq4;
    bnpart[((b * 2 + h) * 64 + tid) * 2]     = s;
    bnpart[((b * 2 + h) * 64 + tid) * 2 + 1] = q;
  }
}

// ---------------------------------------------------------------------------
// K4: reduce bnpart (2048 block-pairs x 2 halves x 64 rows) -> coeff
// ---------------------------------------------------------------------------
__global__ __launch_bounds__(256) void k4_stats(
    const float* __restrict__ bnpart, const float* __restrict__ bnw,
    const float* __restrict__ bnb, float* __restrict__ coeff)
{
  const int o = blockIdx.x, tid = threadIdx.x;
  float sr = 0.f, qr = 0.f, si = 0.f, qi = 0.f;
  for (int b = tid; b < 2048; b += 256) {
    const float* p = bnpart + ((size_t)(b * 2 + 0) * 64 + o) * 2;   // h=0: real rows
    sr += p[0]; qr += p[1];
    const float* p2 = bnpart + ((size_t)(b * 2 + 1) * 64 + o) * 2;  // h=1: imag rows
    si += p2[0]; qi += p2[1];
  }
#pragma unroll
  for (int d = 1; d < 64; d <<= 1) {
    sr += __shfl_xor(sr, d); qr += __shfl_xor(qr, d);
    si += __shfl_xor(si, d); qi += __shfl_xor(qi, d);
  }
  __shared__ float red[4][4];
  int lane = tid & 63, wv = tid >> 6;
  if (lane == 0) { red[wv][0] = sr; red[wv][1] = qr; red[wv][2] = si; red[wv][3] = qi; }
  __syncthreads();
  if (tid == 0) {
    sr = red[0][0] + red[1][0] + red[2][0] + red[3][0];
    qr = red[0][1] + red[1][1] + red[2][1] + red[3][1];
    si = red[0][2] + red[1][2] + red[2][2] + red[3][2];
    qi = red[0][3] + red[1][3] + red[2][3] + red[3][3];
    const float invM = 1.f / (float)((size_t)NN * TTOT * VV);
    float mur = sr * invM, mui = si * invM;
    float var = (qr + qi) * invM - mur * mur - mui * mui;
    float inv = rsqrtf(var + 1e-5f);
    coeff[o * 4 + 0] = mur; coeff[o * 4 + 1] = mui;
    coeff[o * 4 + 2] = inv * bnw[o]; coeff[o * 4 + 3] = bnb[o];
  }
}

// ---------------------------------------------------------------------------
// K5: yn = (y - mu)*scale + shift + x  (in-place on d_out, vectorized)
// ---------------------------------------------------------------------------
__global__ __launch_bounds__(256) void k5_norm(
    const float* __restrict__ xr, const float* __restrict__ xi,
    const float* __restrict__ coeff, float* __restrict__ out)
{
  size_t idx0 = ((size_t)blockIdx.x * 256 + threadIdx.x) * 4;
  size_t stride = (size_t)gridDim.x * 256 * 4;
  for (size_t e = idx0; e < PLANE; e += stride) {
    int o = (int)((e / TV) & 63);
    float4 cf = *(const float4*)&coeff[o * 4];
    float4 yr = *(float4*)&out[e];
    float4 yi = *(float4*)&out[PLANE + e];
    float4 vr = *(const float4*)&xr[e];
    float4 vi = *(const float4*)&xi[e];
    yr.x = (yr.x - cf.x) * cf.z + cf.w + vr.x;
    yr.y = (yr.y - cf.x) * cf.z + cf.w + vr.y;
    yr.z = (yr.z - cf.x) * cf.z + cf.w + vr.z;
    yr.w = (yr.w - cf.x) * cf.z + cf.w + vr.w;
    yi.x = (yi.x - cf.y) * cf.z + vi.x;
    yi.y = (yi.y - cf.y) * cf.z + vi.y;
    yi.z = (yi.z - cf.y) * cf.z + vi.z;
    yi.w = (yi.w - cf.y) * cf.z + vi.w;
    *(float4*)&out[e] = yr;
    *(float4*)&out[PLANE + e] = yi;
  }
}

// ---------------------------------------------------------------------------
extern "C" void kernel_launch(void* const* d_in, const int* in_sizes, int n_in,
                              void* d_out, int out_size, void* d_ws, size_t ws_size,
                              hipStream_t stream) {
  const float* xr  = (const float*)d_in[0];
  const float* xi  = (const float*)d_in[1];
  const float* Aw  = (const float*)d_in[2];
  const float* PA  = (const float*)d_in[3];
  const float* Wa  = (const float*)d_in[4];
  const float* ba  = (const float*)d_in[5];
  const float* Wb  = (const float*)d_in[6];
  const float* bb  = (const float*)d_in[7];
  const float* Wd  = (const float*)d_in[8];
  const float* bd  = (const float*)d_in[9];
  const float* bnw = (const float*)d_in[10];
  const float* bnb = (const float*)d_in[11];
  float* out = (float*)d_out;
  float* ws = (float*)d_ws;

  // ws layout (floats). bnpart aliases Spart (Spart dead after k2).
  float*    Spart  = ws;                         // 7,680,000 floats
  float*    bnpart = ws;                         // 524,288 floats (alias)
  ushort_t* sfrag  = (ushort_t*)(ws + 7680000);  // 196,608 ushorts
  ushort_t* wfrag  = (ushort_t*)(ws + 7778304);  // 49,152 ushorts
  ushort_t* wab    = (ushort_t*)(ws + 7802880);  // 24,576 ushorts
  float*    coeff  = ws + 7815168;               // 256 floats
  // total ≈ 31.3 MB

  k0_wfrag<<<NS, 256, 0, stream>>>(Wd, Wa, Wb, wfrag, wab);
  k1_spart<<<dim3(64, NN), 256, 0, stream>>>(xr, xi, wab, ba, bb, Spart);
  k2_softmax<<<dim3(NS, NN), 256, 0, stream>>>(Spart, Aw, PA, sfrag);
  k3_y<<<dim3(128, NN), 256, 0, stream>>>(xr, xi, sfrag, wfrag, bd, out, bnpart);
  k4_stats<<<64, 256, 0, stream>>>(bnpart, bnw, bnb, coeff);
  k5_norm<<<6400, 256, 0, stream>>>(xr, xi, coeff, out);
}

// Round 16
// 248.709 us; speedup vs baseline: 1.0317x; 1.0238x over previous
//
#include <hip/hip_runtime.h>
#include <hip/hip_bf16.h>
#include <stdint.h>

#define NN 32
#define CC 64
#define TTOT 256
#define VV 25
#define NS 3
constexpr int TV  = TTOT * VV;            // 6400
constexpr int CTV = CC * TV;              // 409600
constexpr size_t PLANE = (size_t)NN * CTV; // 13107200

typedef unsigned short ushort_t;
using short8 = __attribute__((ext_vector_type(8))) short;
using f32x4  = __attribute__((ext_vector_type(4))) float;

static __device__ __forceinline__ ushort_t f2bf(float f) {
  __hip_bfloat16 h = __float2bfloat16(f);
  return reinterpret_cast<ushort_t&>(h);
}
static __device__ __forceinline__ float bf2f(ushort_t h) {
  union { uint32_t u; float f; } v; v.u = ((uint32_t)h) << 16;
  return v.f;
}
// element offset into a [row][128] bf16 tile, XOR-swizzled (byte ^= (row&7)<<4)
static __device__ __forceinline__ int SWZ(int row, int k) {
  return ((row << 7) + k) ^ ((row & 7) << 3);
}
static __device__ __forceinline__ f32x4 mfma16(short8 a, short8 b, f32x4 c) {
  return __builtin_amdgcn_mfma_f32_16x16x32_bf16(a, b, c, 0, 0, 0);
}
static __device__ __forceinline__ short8 negbf8(short8 x) {
  short8 r;
#pragma unroll
  for (int j = 0; j < 8; ++j) r[j] = x[j] ^ (short)0x8000;
  return r;
}

// ---------------------------------------------------------------------------
// K0: pre-fragment Wd (k'=2c+comp interleaved) and Wa/Wb (k=c planar) to bf16
// ---------------------------------------------------------------------------
__global__ __launch_bounds__(256) void k0_wfrag(
    const float* __restrict__ Wd, const float* __restrict__ Wa,
    const float* __restrict__ Wb, ushort_t* __restrict__ wfrag,
    ushort_t* __restrict__ wab)
{
  const int i = blockIdx.x;
  for (int e = threadIdx.x; e < 16384; e += 256) {
    int ot = e >> 11, m = (e >> 9) & 3, l = (e >> 3) & 63, j = e & 7;
    int r  = ot * 16 + (l & 15);
    int c = m * 16 + ((l >> 4) << 2) + (j >> 1), comp = j & 1;
    wfrag[(size_t)i * 16384 + e] = f2bf(Wd[(size_t)i * 16384 + r * 128 + comp * 64 + c]);
  }
  for (int e = threadIdx.x; e < 8192; e += 256) {
    int mt = e >> 11, ks = (e >> 9) & 3, l = (e >> 3) & 63, j = e & 7;
    int r  = mt * 16 + (l & 15);
    int kp = ks * 32 + ((l >> 4) << 3) + j;
    float v = (r < 32) ? Wa[((size_t)i * 32 + r) * 128 + kp]
                       : Wb[((size_t)i * 32 + (r - 32)) * 128 + kp];
    wab[(size_t)i * 8192 + e] = f2bf(v);
  }
}

// ---------------------------------------------------------------------------
// K1: per (n, tc) with 4 t's. Merged i-loop, 2 barriers. LDS 80KB.
// Spart[i][n][tc][625][2]
// ---------------------------------------------------------------------------
__global__ __launch_bounds__(256) void k1_spart(
    const float* __restrict__ xr, const float* __restrict__ xi,
    const ushort_t* __restrict__ wab, const float* __restrict__ ba,
    const float* __restrict__ bb, float* __restrict__ Spart)
{
  const int tc = blockIdx.x, n = blockIdx.y;
  const int tid = threadIdx.x, lane = tid & 63, wv = tid >> 6;
  const int r16 = lane & 15, gw = lane >> 4;
  __shared__ alignas(16) ushort_t zc[128 * 128];
  __shared__ alignas(16) ushort_t Ga[NS][32 * 128];
  __shared__ alignas(16) ushort_t Gb[NS][32 * 128];

  for (int e4 = tid; e4 < 128 * 25; e4 += 256) {
    int c = e4 / 25, q = e4 % 25;
    const float* src = (c < 64) ? xr : xi;
    float4 w = *(const float4*)&src[(size_t)n * CTV + (c & 63) * TV + tc * 100 + q * 4];
#pragma unroll
    for (int jj = 0; jj < 4; ++jj) {
      int g = q * 4 + jj, t = g / 25, v = g - t * 25;
      zc[SWZ(t * 32 + v, c)] = f2bf(((const float*)&w)[jj]);
    }
  }
  for (int e = tid; e < 28 * 128; e += 256) {
    int r7 = e >> 7, c = e & 127;
    int t = r7 / 7, vv = 25 + r7 % 7;
    zc[SWZ(t * 32 + vv, c)] = 0;
  }
  __syncthreads();

#pragma unroll 1
  for (int i = 0; i < NS; ++i) {
    short8 afr[4];
#pragma unroll
    for (int ks = 0; ks < 4; ++ks)
      afr[ks] = *(const short8*)&wab[((((size_t)i * 4 + wv) * 4 + ks) * 64 + lane) * 8];
    float bias[4];
#pragma unroll
    for (int j = 0; j < 4; ++j) {
      int row = wv * 16 + gw * 4 + j;
      bias[j] = (row < 32) ? ba[i * 32 + row] : bb[i * 32 + (row - 32)];
    }
    ushort_t* gbuf = (wv < 2) ? Ga[i] : Gb[i];
    const int half = (wv & 1) * 64;
    for (int nt = 0; nt < 8; ++nt) {
      f32x4 acc = {0.f, 0.f, 0.f, 0.f};
      const int brow = nt * 16 + r16;
#pragma unroll
      for (int ks = 0; ks < 4; ++ks) {
        short8 bfr = *(const short8*)&zc[SWZ(brow, ks * 32 + gw * 8)];
        acc = mfma16(afr[ks], bfr, acc);
      }
      int pos2 = nt * 16 + r16;
      int t = pos2 >> 5, v = pos2 & 31;
      int k0w = half + t * 16 + gw * 4;
      uint32_t w0 = (uint32_t)f2bf(acc[0] + bias[0]) | ((uint32_t)f2bf(acc[1] + bias[1]) << 16);
      uint32_t w1 = (uint32_t)f2bf(acc[2] + bias[2]) | ((uint32_t)f2bf(acc[3] + bias[3]) << 16);
      uint2 pk; pk.x = w0; pk.y = w1;
      *(uint2*)&gbuf[SWZ(v, k0w)] = pk;
    }
  }
  __syncthreads();

  const int mu = wv >> 1, nv = wv & 1;
  const int urow = mu * 16 + r16;
  const int vrow = nv * 16 + r16;
#pragma unroll 1
  for (int i = 0; i < NS; ++i) {
    f32x4 Prr = {0.f,0.f,0.f,0.f}, Pii = {0.f,0.f,0.f,0.f};
    f32x4 Pri = {0.f,0.f,0.f,0.f}, Pir = {0.f,0.f,0.f,0.f};
#pragma unroll
    for (int ks = 0; ks < 2; ++ks) {
      int ko = ks * 32 + gw * 8;
      short8 arF = *(const short8*)&Ga[i][SWZ(urow, ko)];
      short8 aiF = *(const short8*)&Ga[i][SWZ(urow, 64 + ko)];
      short8 brF = *(const short8*)&Gb[i][SWZ(vrow, ko)];
      short8 biF = *(const short8*)&Gb[i][SWZ(vrow, 64 + ko)];
      Prr = mfma16(arF, brF, Prr);
      Pii = mfma16(aiF, biF, Pii);
      Pri = mfma16(arF, biF, Pri);
      Pir = mfma16(aiF, brF, Pir);
    }
#pragma unroll
    for (int j = 0; j < 4; ++j) {
      int u = mu * 16 + gw * 4 + j;
      int v = nv * 16 + r16;
      if (u < VV && v < VV) {
        size_t idx = ((((size_t)i * NN + n) * 64 + tc) * 625 + u * 25 + v) * 2;
        Spart[idx]     = Prr[j] - Pii[j];
        Spart[idx + 1] = Pri[j] + Pir[j];
      }
    }
  }
}

// ---------------------------------------------------------------------------
// K2a: partial tc-reduction with full-GPU parallelism.
// grid (8 chunks, 96 in). Block sums 8 consecutive tc slabs (coalesced).
// Spart2[in][chunk][1250]
// ---------------------------------------------------------------------------
__global__ __launch_bounds__(256) void k2a_reduce(
    const float* __restrict__ Spart, float* __restrict__ Spart2)
{
  const int chunk = blockIdx.x, in = blockIdx.y, tid = threadIdx.x;
  const float* base = Spart + ((size_t)in * 64 + chunk * 8) * 1250;
  float* outp = Spart2 + ((size_t)in * 8 + chunk) * 1250;
  for (int e = tid; e < 1250; e += 256) {
    float s = 0.f;
#pragma unroll
    for (int k = 0; k < 8; ++k) s += base[(size_t)k * 1250 + e];
    outp[e] = s;
  }
}

// ---------------------------------------------------------------------------
// K2b: reduce 8 partials, /4096, complex softmax over u, + (A+PA),
//     emit packed bf16 S-fragments. sfrag[i][n][m(2)][nt(2)][lane(64)][j(8)]
// ---------------------------------------------------------------------------
__global__ __launch_bounds__(256) void k2b_softmax(
    const float* __restrict__ Spart2, const float* __restrict__ Aw,
    const float* __restrict__ PA, ushort_t* __restrict__ sfrag)
{
  const int i = blockIdx.x, n = blockIdx.y, tid = threadIdx.x;
  __shared__ float ez[625 * 2];
  __shared__ float den[25 * 2];
  const float* base = Spart2 + ((size_t)(i * NN + n)) * 8 * 1250;
  for (int e = tid; e < 625; e += 256) {
    float sr = 0.f, si = 0.f;
#pragma unroll
    for (int k = 0; k < 8; ++k) {
      sr += base[(size_t)k * 1250 + e * 2];
      si += base[(size_t)k * 1250 + e * 2 + 1];
    }
    sr *= (1.f / 4096.f); si *= (1.f / 4096.f);
    float m = expf(sr);
    ez[e * 2] = m * cosf(si);
    ez[e * 2 + 1] = m * sinf(si);
  }
  __syncthreads();
  if (tid < 25) {
    float dr = 0.f, di = 0.f;
    for (int u = 0; u < 25; ++u) { dr += ez[(u * 25 + tid) * 2]; di += ez[(u * 25 + tid) * 2 + 1]; }
    float inv = 1.f / (dr * dr + di * di);
    den[tid * 2] = dr * inv; den[tid * 2 + 1] = -di * inv;
  }
  __syncthreads();
  for (int e = tid; e < 625; e += 256) {
    int v = e % 25;
    float er = ez[e * 2], ei = ez[e * 2 + 1];
    float dr = den[v * 2], di = den[v * 2 + 1];
    float outr = er * dr - ei * di + Aw[i * 625 + e] + PA[i * 625 + e];
    float outi = er * di + ei * dr;
    ez[e * 2] = outr; ez[e * 2 + 1] = outi;
  }
  __syncthreads();
  for (int e = tid; e < 256; e += 256) {
    int l = e & 63, nt = (e >> 6) & 1, m = e >> 7;
    int u0 = (l >> 4) << 3, v = nt * 16 + (l & 15);
    short8 pk;
#pragma unroll
    for (int j = 0; j < 8; ++j) {
      int u = u0 + j;
      float val = 0.f;
      if (u < VV && v < VV)
        val = (m == 0) ? ez[(u * 25 + v) * 2] : ez[(u * 25 + v) * 2 + 1];
      pk[j] = (short)f2bf(val);
    }
    *(short8*)&sfrag[((size_t)(i * NN + n) * 256 + e) * 8] = pk;
  }
}

// ---------------------------------------------------------------------------
// K3: R13 structure (best measured) + setprio around phase-B MFMA cluster.
// Block = (tq8, n): 512 thr / 8 waves; wave wv owns t = tq8*8+wv.
// ---------------------------------------------------------------------------
__global__ __launch_bounds__(512) void k3_y(
    const float* __restrict__ xr, const float* __restrict__ xi,
    const ushort_t* __restrict__ sfrag, const ushort_t* __restrict__ wfrag,
    const float* __restrict__ bd, float* __restrict__ out,
    float* __restrict__ bnpart)
{
  const int tq8 = blockIdx.x, n = blockIdx.y;
  const int tid = threadIdx.x, lane = tid & 63, wv = tid >> 6;
  const int r16 = lane & 15, gw = lane >> 4;
  __shared__ alignas(16) ushort_t wlds[49152]; // 96KB: xs (first 64KB) then W
  __shared__ float stats[8][128][2];           // 8KB

  // ---- stage x for 8 t's into wlds[0..32768) as xs[2][128][128] (swizzled)
  {
    ushort_t* xs = wlds;
    for (int e4 = tid; e4 < 128 * 50; e4 += 512) {
      int c = e4 / 50, q = e4 % 50;
      const float* src = (c < 64) ? xr : xi;
      float4 w = *(const float4*)&src[(size_t)n * CTV + (c & 63) * TV + tq8 * 200 + q * 4];
#pragma unroll
      for (int jj = 0; jj < 4; ++jj) {
        int g = q * 4 + jj, t = g / 25, u = g - t * 25;
        xs[(t >> 2) * 16384 + SWZ(c, (t & 3) * 32 + u)] = f2bf(((const float*)&w)[jj]);
      }
    }
    for (int e = tid; e < 128 * 56; e += 512) { // pad u=25..31, all 8 t
      int c = e / 56, r = e % 56;
      int t = r / 7, u = 25 + r % 7;
      xs[(t >> 2) * 16384 + SWZ(c, (t & 3) * 32 + u)] = 0;
    }
  }
  __syncthreads();

  // hoist x A-frags (wave wv <-> local t = wv)
  const int tl = wv & 3, th = wv >> 2;
  const int kx = tl * 32 + gw * 8;
  short8 axr[4], axi[4];
#pragma unroll
  for (int tile = 0; tile < 4; ++tile) {
    axr[tile] = *(const short8*)&wlds[th * 16384 + SWZ(tile * 16 + r16, kx)];
    axi[tile] = *(const short8*)&wlds[th * 16384 + SWZ(64 + tile * 16 + r16, kx)];
  }
  __syncthreads(); // xs dead

  // stage ALL weights (3 i's, 96KB): 12 coalesced b128 per thread
  {
    short8 tmp[12];
#pragma unroll
    for (int q = 0; q < 12; ++q)
      tmp[q] = *(const short8*)&wfrag[(size_t)(q * 512 + tid) * 8];
#pragma unroll
    for (int q = 0; q < 12; ++q)
      *(short8*)&wlds[(size_t)(q * 512 + tid) * 8] = tmp[q];
  }
  __syncthreads(); // weights ready; loop below is barrier-free

  f32x4 acc[8][2];
#pragma unroll
  for (int a = 0; a < 8; ++a) { acc[a][0] = {0.f,0.f,0.f,0.f}; acc[a][1] = {0.f,0.f,0.f,0.f}; }

  auto load_sf = [&](int i, short8 sf[2][2]) {
    const ushort_t* sb = sfrag + (size_t)(i * NN + n) * 2048;
#pragma unroll
    for (int m = 0; m < 2; ++m)
#pragma unroll
      for (int nt = 0; nt < 2; ++nt)
        sf[m][nt] = *(const short8*)&sb[((m * 2 + nt) * 64 + lane) * 8];
  };
  auto compute_i = [&](int i, short8 sf[2][2]) {
    short8 snI[2];
#pragma unroll
    for (int nt = 0; nt < 2; ++nt) snI[nt] = negbf8(sf[1][nt]);
    short8 bp[4][2];
#pragma unroll
    for (int tile = 0; tile < 4; ++tile) {
#pragma unroll
      for (int nt = 0; nt < 2; ++nt) {
        f32x4 zr = {0.f,0.f,0.f,0.f}, zi = {0.f,0.f,0.f,0.f};
        zr = mfma16(axr[tile], sf[0][nt], zr);
        zr = mfma16(axi[tile], snI[nt], zr);
        zi = mfma16(axr[tile], sf[1][nt], zi);
        zi = mfma16(axi[tile], sf[0][nt], zi);
        short8 pk;
#pragma unroll
        for (int j = 0; j < 4; ++j) {
          pk[2 * j]     = (short)f2bf(zr[j]);
          pk[2 * j + 1] = (short)f2bf(zi[j]);
        }
        bp[tile][nt] = pk;
      }
    }
    __builtin_amdgcn_s_setprio(1);
#pragma unroll
    for (int ot = 0; ot < 8; ++ot) {
#pragma unroll
      for (int m = 0; m < 4; ++m) {
        short8 a = *(const short8*)&wlds[((size_t)i * 16384) + (size_t)((ot * 4 + m) * 64 + lane) * 8];
        acc[ot][0] = mfma16(a, bp[m][0], acc[ot][0]);
        acc[ot][1] = mfma16(a, bp[m][1], acc[ot][1]);
      }
    }
    __builtin_amdgcn_s_setprio(0);
  };

  // software-pipelined sfrag: prefetch next i during compute of current
  short8 sfA[2][2], sfB[2][2];
  load_sf(0, sfA);
  load_sf(1, sfB);
  compute_i(0, sfA);
  load_sf(2, sfA);
  compute_i(1, sfB);
  compute_i(2, sfA);

  // epilogue: bias, write y (t = tq8*8+wv), BN partials
  const int t = tq8 * 8 + wv;
#pragma unroll
  for (int ot = 0; ot < 8; ++ot) {
#pragma unroll
    for (int j = 0; j < 4; ++j) {
      int row = ot * 16 + gw * 4 + j;
      float bias = bd[row] + bd[128 + row] + bd[256 + row];
      float s = 0.f, q = 0.f;
#pragma unroll
      for (int nt = 0; nt < 2; ++nt) {
        int v = nt * 16 + r16;
        float val = acc[ot][nt][j] + bias;
        if (v < VV) {
          out[(size_t)(row >> 6) * PLANE + (size_t)n * CTV + (row & 63) * TV + t * VV + v] = val;
          s += val; q += val * val;
        }
      }
#pragma unroll
      for (int d = 1; d < 16; d <<= 1) { s += __shfl_xor(s, d); q += __shfl_xor(q, d); }
      if (r16 == 0) { stats[wv][row][0] = s; stats[wv][row][1] = q; }
    }
  }
  __syncthreads();
  if (tid < 128) {
    float s = 0.f, q = 0.f;
#pragma unroll
    for (int w = 0; w < 8; ++w) { s += stats[w][tid][0]; q += stats[w][tid][1]; }
    size_t b = (size_t)n * 32 + tq8;
    bnpart[(b * 128 + tid) * 2]     = s;
    bnpart[(b * 128 + tid) * 2 + 1] = q;
  }
}

// ---------------------------------------------------------------------------
// K4: reduce bnpart (1024 partials) -> per-channel coeff
// ---------------------------------------------------------------------------
__global__ __launch_bounds__(256) void k4_stats(
    const float* __restrict__ bnpart, const float* __restrict__ bnw,
    const float* __restrict__ bnb, float* __restrict__ coeff)
{
  const int o = blockIdx.x, tid = threadIdx.x;
  float sr = 0.f, qr = 0.f, si = 0.f, qi = 0.f;
  for (int b = tid; b < 1024; b += 256) {
    const float* p = bnpart + ((size_t)b * 128 + o) * 2;
    sr += p[0]; qr += p[1];
    const float* p2 = bnpart + ((size_t)b * 128 + 64 + o) * 2;
    si += p2[0]; qi += p2[1];
  }
#pragma unroll
  for (int d = 1; d < 64; d <<= 1) {
    sr += __shfl_xor(sr, d); qr += __shfl_xor(qr, d);
    si += __shfl_xor(si, d); qi += __shfl_xor(qi, d);
  }
  __shared__ float red[4][4];
  int lane = tid & 63, wv = tid >> 6;
  if (lane == 0) { red[wv][0] = sr; red[wv][1] = qr; red[wv][2] = si; red[wv][3] = qi; }
  __syncthreads();
  if (tid == 0) {
    sr = red[0][0] + red[1][0] + red[2][0] + red[3][0];
    qr = red[0][1] + red[1][1] + red[2][1] + red[3][1];
    si = red[0][2] + red[1][2] + red[2][2] + red[3][2];
    qi = red[0][3] + red[1][3] + red[2][3] + red[3][3];
    const float invM = 1.f / (float)((size_t)NN * TTOT * VV);
    float mur = sr * invM, mui = si * invM;
    float var = (qr + qi) * invM - mur * mur - mui * mui;
    float inv = rsqrtf(var + 1e-5f);
    coeff[o * 4 + 0] = mur; coeff[o * 4 + 1] = mui;
    coeff[o * 4 + 2] = inv * bnw[o]; coeff[o * 4 + 3] = bnb[o];
  }
}

// ---------------------------------------------------------------------------
// K5: yn = (y - mu)*scale + shift + x  (in-place on d_out, vectorized)
// ---------------------------------------------------------------------------
__global__ __launch_bounds__(256) void k5_norm(
    const float* __restrict__ xr, const float* __restrict__ xi,
    const float* __restrict__ coeff, float* __restrict__ out)
{
  size_t idx0 = ((size_t)blockIdx.x * 256 + threadIdx.x) * 4;
  size_t stride = (size_t)gridDim.x * 256 * 4;
  for (size_t e = idx0; e < PLANE; e += stride) {
    int o = (int)((e / TV) & 63);
    float4 cf = *(const float4*)&coeff[o * 4];
    float4 yr = *(float4*)&out[e];
    float4 yi = *(float4*)&out[PLANE + e];
    float4 vr = *(const float4*)&xr[e];
    float4 vi = *(const float4*)&xi[e];
    yr.x = (yr.x - cf.x) * cf.z + cf.w + vr.x;
    yr.y = (yr.y - cf.x) * cf.z + cf.w + vr.y;
    yr.z = (yr.z - cf.x) * cf.z + cf.w + vr.z;
    yr.w = (yr.w - cf.x) * cf.z + cf.w + vr.w;
    yi.x = (yi.x - cf.y) * cf.z + vi.x;
    yi.y = (yi.y - cf.y) * cf.z + vi.y;
    yi.z = (yi.z - cf.y) * cf.z + vi.z;
    yi.w = (yi.w - cf.y) * cf.z + vi.w;
    *(float4*)&out[e] = yr;
    *(float4*)&out[PLANE + e] = yi;
  }
}

// ---------------------------------------------------------------------------
extern "C" void kernel_launch(void* const* d_in, const int* in_sizes, int n_in,
                              void* d_out, int out_size, void* d_ws, size_t ws_size,
                              hipStream_t stream) {
  const float* xr  = (const float*)d_in[0];
  const float* xi  = (const float*)d_in[1];
  const float* Aw  = (const float*)d_in[2];
  const float* PA  = (const float*)d_in[3];
  const float* Wa  = (const float*)d_in[4];
  const float* ba  = (const float*)d_in[5];
  const float* Wb  = (const float*)d_in[6];
  const float* bb  = (const float*)d_in[7];
  const float* Wd  = (const float*)d_in[8];
  const float* bd  = (const float*)d_in[9];
  const float* bnw = (const float*)d_in[10];
  const float* bnb = (const float*)d_in[11];
  float* out = (float*)d_out;
  float* ws = (float*)d_ws;

  // ws layout (floats). bnpart aliases Spart (Spart dead after k2a;
  // Spart2 dead after k2b; k3 writes bnpart into the Spart region).
  float*    Spart  = ws;                         // 7,680,000 floats
  float*    bnpart = ws;                         // 262,144 floats (alias)
  float*    Spart2 = ws + 7680000;               // 960,000 floats
  ushort_t* sfrag  = (ushort_t*)(ws + 8640000);  // 196,608 ushorts
  ushort_t* wfrag  = (ushort_t*)(ws + 8738304);  // 49,152 ushorts
  ushort_t* wab    = (ushort_t*)(ws + 8762880);  // 24,576 ushorts
  float*    coeff  = ws + 8775168;               // 256 floats
  // total ≈ 35.1 MB

  k0_wfrag<<<NS, 256, 0, stream>>>(Wd, Wa, Wb, wfrag, wab);
  k1_spart<<<dim3(64, NN), 256, 0, stream>>>(xr, xi, wab, ba, bb, Spart);
  k2a_reduce<<<dim3(8, NS * NN), 256, 0, stream>>>(Spart, Spart2);
  k2b_softmax<<<dim3(NS, NN), 256, 0, stream>>>(Spart2, Aw, PA, sfrag);
  k3_y<<<dim3(32, NN), 512, 0, stream>>>(xr, xi, sfrag, wfrag, bd, out, bnpart);
  k4_stats<<<64, 256, 0, stream>>>(bnpart, bnw, bnb, coeff);
  k5_norm<<<6400, 256, 0, stream>>>(xr, xi, coeff, out);
}

// Round 17
// 218.756 us; speedup vs baseline: 1.1730x; 1.1369x over previous
//
#include <hip/hip_runtime.h>
#include <hip/hip_bf16.h>
#include <stdint.h>

#define NN 32
#define CC 64
#define TTOT 256
#define VV 25
#define NS 3
constexpr int TV  = TTOT * VV;            // 6400
constexpr int CTV = CC * TV;              // 409600
constexpr size_t PLANE = (size_t)NN * CTV; // 13107200

typedef unsigned short ushort_t;
using short8 = __attribute__((ext_vector_type(8))) short;
using f32x4  = __attribute__((ext_vector_type(4))) float;

static __device__ __forceinline__ ushort_t f2bf(float f) {
  __hip_bfloat16 h = __float2bfloat16(f);
  return reinterpret_cast<ushort_t&>(h);
}
static __device__ __forceinline__ float bf2f(ushort_t h) {
  union { uint32_t u; float f; } v; v.u = ((uint32_t)h) << 16;
  return v.f;
}
// element offset into a [row][128] bf16 tile, XOR-swizzled (byte ^= (row&7)<<4)
static __device__ __forceinline__ int SWZ(int row, int k) {
  return ((row << 7) + k) ^ ((row & 7) << 3);
}
static __device__ __forceinline__ f32x4 mfma16(short8 a, short8 b, f32x4 c) {
  return __builtin_amdgcn_mfma_f32_16x16x32_bf16(a, b, c, 0, 0, 0);
}
static __device__ __forceinline__ short8 negbf8(short8 x) {
  short8 r;
#pragma unroll
  for (int j = 0; j < 8; ++j) r[j] = x[j] ^ (short)0x8000;
  return r;
}

// ---------------------------------------------------------------------------
// K0: pre-fragment Wd (k'=2c+comp interleaved) and Wa/Wb (k=c planar) to bf16
// ---------------------------------------------------------------------------
__global__ __launch_bounds__(256) void k0_wfrag(
    const float* __restrict__ Wd, const float* __restrict__ Wa,
    const float* __restrict__ Wb, ushort_t* __restrict__ wfrag,
    ushort_t* __restrict__ wab)
{
  const int i = blockIdx.x;
  for (int e = threadIdx.x; e < 16384; e += 256) {
    int ot = e >> 11, m = (e >> 9) & 3, l = (e >> 3) & 63, j = e & 7;
    int r  = ot * 16 + (l & 15);
    int c = m * 16 + ((l >> 4) << 2) + (j >> 1), comp = j & 1;
    wfrag[(size_t)i * 16384 + e] = f2bf(Wd[(size_t)i * 16384 + r * 128 + comp * 64 + c]);
  }
  for (int e = threadIdx.x; e < 8192; e += 256) {
    int mt = e >> 11, ks = (e >> 9) & 3, l = (e >> 3) & 63, j = e & 7;
    int r  = mt * 16 + (l & 15);
    int kp = ks * 32 + ((l >> 4) << 3) + j;
    float v = (r < 32) ? Wa[((size_t)i * 32 + r) * 128 + kp]
                       : Wb[((size_t)i * 32 + (r - 32)) * 128 + kp];
    wab[(size_t)i * 8192 + e] = f2bf(v);
  }
}

// ---------------------------------------------------------------------------
// K1: per (n, tc) with 4 t's. Merged i-loop, 2 barriers. LDS 80KB.
// Spart[i][n][tc][625][2]
// ---------------------------------------------------------------------------
__global__ __launch_bounds__(256) void k1_spart(
    const float* __restrict__ xr, const float* __restrict__ xi,
    const ushort_t* __restrict__ wab, const float* __restrict__ ba,
    const float* __restrict__ bb, float* __restrict__ Spart)
{
  const int tc = blockIdx.x, n = blockIdx.y;
  const int tid = threadIdx.x, lane = tid & 63, wv = tid >> 6;
  const int r16 = lane & 15, gw = lane >> 4;
  __shared__ alignas(16) ushort_t zc[128 * 128];
  __shared__ alignas(16) ushort_t Ga[NS][32 * 128];
  __shared__ alignas(16) ushort_t Gb[NS][32 * 128];

  for (int e4 = tid; e4 < 128 * 25; e4 += 256) {
    int c = e4 / 25, q = e4 % 25;
    const float* src = (c < 64) ? xr : xi;
    float4 w = *(const float4*)&src[(size_t)n * CTV + (c & 63) * TV + tc * 100 + q * 4];
#pragma unroll
    for (int jj = 0; jj < 4; ++jj) {
      int g = q * 4 + jj, t = g / 25, v = g - t * 25;
      zc[SWZ(t * 32 + v, c)] = f2bf(((const float*)&w)[jj]);
    }
  }
  for (int e = tid; e < 28 * 128; e += 256) {
    int r7 = e >> 7, c = e & 127;
    int t = r7 / 7, vv = 25 + r7 % 7;
    zc[SWZ(t * 32 + vv, c)] = 0;
  }
  __syncthreads();

#pragma unroll 1
  for (int i = 0; i < NS; ++i) {
    short8 afr[4];
#pragma unroll
    for (int ks = 0; ks < 4; ++ks)
      afr[ks] = *(const short8*)&wab[((((size_t)i * 4 + wv) * 4 + ks) * 64 + lane) * 8];
    float bias[4];
#pragma unroll
    for (int j = 0; j < 4; ++j) {
      int row = wv * 16 + gw * 4 + j;
      bias[j] = (row < 32) ? ba[i * 32 + row] : bb[i * 32 + (row - 32)];
    }
    ushort_t* gbuf = (wv < 2) ? Ga[i] : Gb[i];
    const int half = (wv & 1) * 64;
    for (int nt = 0; nt < 8; ++nt) {
      f32x4 acc = {0.f, 0.f, 0.f, 0.f};
      const int brow = nt * 16 + r16;
#pragma unroll
      for (int ks = 0; ks < 4; ++ks) {
        short8 bfr = *(const short8*)&zc[SWZ(brow, ks * 32 + gw * 8)];
        acc = mfma16(afr[ks], bfr, acc);
      }
      int pos2 = nt * 16 + r16;
      int t = pos2 >> 5, v = pos2 & 31;
      int k0w = half + t * 16 + gw * 4;
      uint32_t w0 = (uint32_t)f2bf(acc[0] + bias[0]) | ((uint32_t)f2bf(acc[1] + bias[1]) << 16);
      uint32_t w1 = (uint32_t)f2bf(acc[2] + bias[2]) | ((uint32_t)f2bf(acc[3] + bias[3]) << 16);
      uint2 pk; pk.x = w0; pk.y = w1;
      *(uint2*)&gbuf[SWZ(v, k0w)] = pk;
    }
  }
  __syncthreads();

  const int mu = wv >> 1, nv = wv & 1;
  const int urow = mu * 16 + r16;
  const int vrow = nv * 16 + r16;
#pragma unroll 1
  for (int i = 0; i < NS; ++i) {
    f32x4 Prr = {0.f,0.f,0.f,0.f}, Pii = {0.f,0.f,0.f,0.f};
    f32x4 Pri = {0.f,0.f,0.f,0.f}, Pir = {0.f,0.f,0.f,0.f};
#pragma unroll
    for (int ks = 0; ks < 2; ++ks) {
      int ko = ks * 32 + gw * 8;
      short8 arF = *(const short8*)&Ga[i][SWZ(urow, ko)];
      short8 aiF = *(const short8*)&Ga[i][SWZ(urow, 64 + ko)];
      short8 brF = *(const short8*)&Gb[i][SWZ(vrow, ko)];
      short8 biF = *(const short8*)&Gb[i][SWZ(vrow, 64 + ko)];
      Prr = mfma16(arF, brF, Prr);
      Pii = mfma16(aiF, biF, Pii);
      Pri = mfma16(arF, biF, Pri);
      Pir = mfma16(aiF, brF, Pir);
    }
#pragma unroll
    for (int j = 0; j < 4; ++j) {
      int u = mu * 16 + gw * 4 + j;
      int v = nv * 16 + r16;
      if (u < VV && v < VV) {
        size_t idx = ((((size_t)i * NN + n) * 64 + tc) * 625 + u * 25 + v) * 2;
        Spart[idx]     = Prr[j] - Pii[j];
        Spart[idx + 1] = Pri[j] + Pir[j];
      }
    }
  }
}

// ---------------------------------------------------------------------------
// K2: reduce Spart over tc, /4096, complex softmax over u, + (A+PA),
//     emit packed bf16 S-fragments. sfrag[i][n][m(2)][nt(2)][lane(64)][j(8)]
// ---------------------------------------------------------------------------
__global__ __launch_bounds__(256) void k2_softmax(
    const float* __restrict__ Spart, const float* __restrict__ Aw,
    const float* __restrict__ PA, ushort_t* __restrict__ sfrag)
{
  const int i = blockIdx.x, n = blockIdx.y, tid = threadIdx.x;
  __shared__ float ez[625 * 2];
  __shared__ float den[25 * 2];
  for (int e = tid; e < 625; e += 256) {
    float sr = 0.f, si = 0.f;
    const float* p = Spart + (((size_t)i * NN + n) * 64 * 625 + e) * 2;
    for (int tcb = 0; tcb < 64; ++tcb) { sr += p[0]; si += p[1]; p += 625 * 2; }
    sr *= (1.f / 4096.f); si *= (1.f / 4096.f);
    float m = expf(sr);
    ez[e * 2] = m * cosf(si);
    ez[e * 2 + 1] = m * sinf(si);
  }
  __syncthreads();
  if (tid < 25) {
    float dr = 0.f, di = 0.f;
    for (int u = 0; u < 25; ++u) { dr += ez[(u * 25 + tid) * 2]; di += ez[(u * 25 + tid) * 2 + 1]; }
    float inv = 1.f / (dr * dr + di * di);
    den[tid * 2] = dr * inv; den[tid * 2 + 1] = -di * inv;
  }
  __syncthreads();
  for (int e = tid; e < 625; e += 256) {
    int v = e % 25;
    float er = ez[e * 2], ei = ez[e * 2 + 1];
    float dr = den[v * 2], di = den[v * 2 + 1];
    float outr = er * dr - ei * di + Aw[i * 625 + e] + PA[i * 625 + e];
    float outi = er * di + ei * dr;
    ez[e * 2] = outr; ez[e * 2 + 1] = outi;
  }
  __syncthreads();
  for (int e = tid; e < 256; e += 256) {
    int l = e & 63, nt = (e >> 6) & 1, m = e >> 7;
    int u0 = (l >> 4) << 3, v = nt * 16 + (l & 15);
    short8 pk;
#pragma unroll
    for (int j = 0; j < 8; ++j) {
      int u = u0 + j;
      float val = 0.f;
      if (u < VV && v < VV)
        val = (m == 0) ? ez[(u * 25 + v) * 2] : ez[(u * 25 + v) * 2 + 1];
      pk[j] = (short)f2bf(val);
    }
    *(short8*)&sfrag[((size_t)(i * NN + n) * 256 + e) * 8] = pk;
  }
}

// ---------------------------------------------------------------------------
// K3: R13 structure + setprio. Epilogue packs (yr, yi) as bf16 u32 pairs into
// the first half of `out` (element-exclusive, fully rewritten every launch).
// Block = (tq8, n): 512 thr / 8 waves; wave wv owns t = tq8*8+wv.
// ---------------------------------------------------------------------------
__global__ __launch_bounds__(512) void k3_y(
    const float* __restrict__ xr, const float* __restrict__ xi,
    const ushort_t* __restrict__ sfrag, const ushort_t* __restrict__ wfrag,
    const float* __restrict__ bd, uint32_t* __restrict__ ypair,
    float* __restrict__ bnpart)
{
  const int tq8 = blockIdx.x, n = blockIdx.y;
  const int tid = threadIdx.x, lane = tid & 63, wv = tid >> 6;
  const int r16 = lane & 15, gw = lane >> 4;
  __shared__ alignas(16) ushort_t wlds[49152]; // 96KB: xs (first 64KB) then W
  __shared__ float stats[8][128][2];           // 8KB

  // ---- stage x for 8 t's into wlds[0..32768) as xs[2][128][128] (swizzled)
  {
    ushort_t* xs = wlds;
    for (int e4 = tid; e4 < 128 * 50; e4 += 512) {
      int c = e4 / 50, q = e4 % 50;
      const float* src = (c < 64) ? xr : xi;
      float4 w = *(const float4*)&src[(size_t)n * CTV + (c & 63) * TV + tq8 * 200 + q * 4];
#pragma unroll
      for (int jj = 0; jj < 4; ++jj) {
        int g = q * 4 + jj, t = g / 25, u = g - t * 25;
        xs[(t >> 2) * 16384 + SWZ(c, (t & 3) * 32 + u)] = f2bf(((const float*)&w)[jj]);
      }
    }
    for (int e = tid; e < 128 * 56; e += 512) { // pad u=25..31, all 8 t
      int c = e / 56, r = e % 56;
      int t = r / 7, u = 25 + r % 7;
      xs[(t >> 2) * 16384 + SWZ(c, (t & 3) * 32 + u)] = 0;
    }
  }
  __syncthreads();

  // hoist x A-frags (wave wv <-> local t = wv)
  const int tl = wv & 3, th = wv >> 2;
  const int kx = tl * 32 + gw * 8;
  short8 axr[4], axi[4];
#pragma unroll
  for (int tile = 0; tile < 4; ++tile) {
    axr[tile] = *(const short8*)&wlds[th * 16384 + SWZ(tile * 16 + r16, kx)];
    axi[tile] = *(const short8*)&wlds[th * 16384 + SWZ(64 + tile * 16 + r16, kx)];
  }
  __syncthreads(); // xs dead

  // stage ALL weights (3 i's, 96KB): 12 coalesced b128 per thread
  {
    short8 tmp[12];
#pragma unroll
    for (int q = 0; q < 12; ++q)
      tmp[q] = *(const short8*)&wfrag[(size_t)(q * 512 + tid) * 8];
#pragma unroll
    for (int q = 0; q < 12; ++q)
      *(short8*)&wlds[(size_t)(q * 512 + tid) * 8] = tmp[q];
  }
  __syncthreads(); // weights ready; loop below is barrier-free

  f32x4 acc[8][2];
#pragma unroll
  for (int a = 0; a < 8; ++a) { acc[a][0] = {0.f,0.f,0.f,0.f}; acc[a][1] = {0.f,0.f,0.f,0.f}; }

  auto load_sf = [&](int i, short8 sf[2][2]) {
    const ushort_t* sb = sfrag + (size_t)(i * NN + n) * 2048;
#pragma unroll
    for (int m = 0; m < 2; ++m)
#pragma unroll
      for (int nt = 0; nt < 2; ++nt)
        sf[m][nt] = *(const short8*)&sb[((m * 2 + nt) * 64 + lane) * 8];
  };
  auto compute_i = [&](int i, short8 sf[2][2]) {
    short8 snI[2];
#pragma unroll
    for (int nt = 0; nt < 2; ++nt) snI[nt] = negbf8(sf[1][nt]);
    short8 bp[4][2];
#pragma unroll
    for (int tile = 0; tile < 4; ++tile) {
#pragma unroll
      for (int nt = 0; nt < 2; ++nt) {
        f32x4 zr = {0.f,0.f,0.f,0.f}, zi = {0.f,0.f,0.f,0.f};
        zr = mfma16(axr[tile], sf[0][nt], zr);
        zr = mfma16(axi[tile], snI[nt], zr);
        zi = mfma16(axr[tile], sf[1][nt], zi);
        zi = mfma16(axi[tile], sf[0][nt], zi);
        short8 pk;
#pragma unroll
        for (int j = 0; j < 4; ++j) {
          pk[2 * j]     = (short)f2bf(zr[j]);
          pk[2 * j + 1] = (short)f2bf(zi[j]);
        }
        bp[tile][nt] = pk;
      }
    }
    __builtin_amdgcn_s_setprio(1);
#pragma unroll
    for (int ot = 0; ot < 8; ++ot) {
#pragma unroll
      for (int m = 0; m < 4; ++m) {
        short8 a = *(const short8*)&wlds[((size_t)i * 16384) + (size_t)((ot * 4 + m) * 64 + lane) * 8];
        acc[ot][0] = mfma16(a, bp[m][0], acc[ot][0]);
        acc[ot][1] = mfma16(a, bp[m][1], acc[ot][1]);
      }
    }
    __builtin_amdgcn_s_setprio(0);
  };

  // software-pipelined sfrag: prefetch next i during compute of current
  short8 sfA[2][2], sfB[2][2];
  load_sf(0, sfA);
  load_sf(1, sfB);
  compute_i(0, sfA);
  load_sf(2, sfA);
  compute_i(1, sfB);
  compute_i(2, sfA);

  // epilogue: bias, pack (yr,yi) bf16 u32 pairs, BN partials.
  // ot in 0..3 = real rows o; ot+4 = imag rows 64+o (same thread).
  const int t = tq8 * 8 + wv;
#pragma unroll
  for (int ot = 0; ot < 4; ++ot) {
#pragma unroll
    for (int j = 0; j < 4; ++j) {
      int o = ot * 16 + gw * 4 + j;           // output channel 0..63
      float biasR = bd[o] + bd[128 + o] + bd[256 + o];
      float biasI = bd[64 + o] + bd[192 + o] + bd[320 + o];
      float sR = 0.f, qR = 0.f, sI = 0.f, qI = 0.f;
#pragma unroll
      for (int nt = 0; nt < 2; ++nt) {
        int v = nt * 16 + r16;
        float vr_ = acc[ot][nt][j] + biasR;
        float vi_ = acc[ot + 4][nt][j] + biasI;
        if (v < VV) {
          uint32_t pk = (uint32_t)f2bf(vr_) | ((uint32_t)f2bf(vi_) << 16);
          ypair[(size_t)n * CTV + (size_t)o * TV + t * VV + v] = pk;
          sR += vr_; qR += vr_ * vr_;
          sI += vi_; qI += vi_ * vi_;
        }
      }
#pragma unroll
      for (int d = 1; d < 16; d <<= 1) {
        sR += __shfl_xor(sR, d); qR += __shfl_xor(qR, d);
        sI += __shfl_xor(sI, d); qI += __shfl_xor(qI, d);
      }
      if (r16 == 0) {
        stats[wv][o][0] = sR;      stats[wv][o][1] = qR;
        stats[wv][64 + o][0] = sI; stats[wv][64 + o][1] = qI;
      }
    }
  }
  __syncthreads();
  if (tid < 128) {
    float s = 0.f, q = 0.f;
#pragma unroll
    for (int w = 0; w < 8; ++w) { s += stats[w][tid][0]; q += stats[w][tid][1]; }
    size_t b = (size_t)n * 32 + tq8;
    bnpart[(b * 128 + tid) * 2]     = s;
    bnpart[(b * 128 + tid) * 2 + 1] = q;
  }
}

// ---------------------------------------------------------------------------
// K4: reduce bnpart (1024 partials) -> per-channel coeff
// ---------------------------------------------------------------------------
__global__ __launch_bounds__(256) void k4_stats(
    const float* __restrict__ bnpart, const float* __restrict__ bnw,
    const float* __restrict__ bnb, float* __restrict__ coeff)
{
  const int o = blockIdx.x, tid = threadIdx.x;
  float sr = 0.f, qr = 0.f, si = 0.f, qi = 0.f;
  for (int b = tid; b < 1024; b += 256) {
    const float* p = bnpart + ((size_t)b * 128 + o) * 2;
    sr += p[0]; qr += p[1];
    const float* p2 = bnpart + ((size_t)b * 128 + 64 + o) * 2;
    si += p2[0]; qi += p2[1];
  }
#pragma unroll
  for (int d = 1; d < 64; d <<= 1) {
    sr += __shfl_xor(sr, d); qr += __shfl_xor(qr, d);
    si += __shfl_xor(si, d); qi += __shfl_xor(qi, d);
  }
  __shared__ float red[4][4];
  int lane = tid & 63, wv = tid >> 6;
  if (lane == 0) { red[wv][0] = sr; red[wv][1] = qr; red[wv][2] = si; red[wv][3] = qi; }
  __syncthreads();
  if (tid == 0) {
    sr = red[0][0] + red[1][0] + red[2][0] + red[3][0];
    qr = red[0][1] + red[1][1] + red[2][1] + red[3][1];
    si = red[0][2] + red[1][2] + red[2][2] + red[3][2];
    qi = red[0][3] + red[1][3] + red[2][3] + red[3][3];
    const float invM = 1.f / (float)((size_t)NN * TTOT * VV);
    float mur = sr * invM, mui = si * invM;
    float var = (qr + qi) * invM - mur * mur - mui * mui;
    float inv = rsqrtf(var + 1e-5f);
    coeff[o * 4 + 0] = mur; coeff[o * 4 + 1] = mui;
    coeff[o * 4 + 2] = inv * bnw[o]; coeff[o * 4 + 3] = bnb[o];
  }
}

// ---------------------------------------------------------------------------
// K5: read bf16 (yr,yi) pairs from out's first half, normalize, add residual,
// write fp32 planes. Thread e reads u32[e] then writes float out[e] (same
// address, element-exclusive) and out[PLANE+e].
// ---------------------------------------------------------------------------
__global__ __launch_bounds__(256) void k5_norm(
    const float* __restrict__ xr, const float* __restrict__ xi,
    const float* __restrict__ coeff, float* __restrict__ out)
{
  uint32_t* yp = (uint32_t*)out;
  size_t idx0 = ((size_t)blockIdx.x * 256 + threadIdx.x) * 4;
  size_t stride = (size_t)gridDim.x * 256 * 4;
  for (size_t e = idx0; e < PLANE; e += stride) {
    int o = (int)((e / TV) & 63);
    float4 cf = *(const float4*)&coeff[o * 4];
    uint4 y4 = *(uint4*)&yp[e];
    float4 vr = *(const float4*)&xr[e];
    float4 vi = *(const float4*)&xi[e];
    float4 yr, yi;
    yr.x = bf2f((ushort_t)(y4.x & 0xffff)); yi.x = bf2f((ushort_t)(y4.x >> 16));
    yr.y = bf2f((ushort_t)(y4.y & 0xffff)); yi.y = bf2f((ushort_t)(y4.y >> 16));
    yr.z = bf2f((ushort_t)(y4.z & 0xffff)); yi.z = bf2f((ushort_t)(y4.z >> 16));
    yr.w = bf2f((ushort_t)(y4.w & 0xffff)); yi.w = bf2f((ushort_t)(y4.w >> 16));
    yr.x = (yr.x - cf.x) * cf.z + cf.w + vr.x;
    yr.y = (yr.y - cf.x) * cf.z + cf.w + vr.y;
    yr.z = (yr.z - cf.x) * cf.z + cf.w + vr.z;
    yr.w = (yr.w - cf.x) * cf.z + cf.w + vr.w;
    yi.x = (yi.x - cf.y) * cf.z + vi.x;
    yi.y = (yi.y - cf.y) * cf.z + vi.y;
    yi.z = (yi.z - cf.y) * cf.z + vi.z;
    yi.w = (yi.w - cf.y) * cf.z + vi.w;
    *(float4*)&out[e] = yr;
    *(float4*)&out[PLANE + e] = yi;
  }
}

// ---------------------------------------------------------------------------
extern "C" void kernel_launch(void* const* d_in, const int* in_sizes, int n_in,
                              void* d_out, int out_size, void* d_ws, size_t ws_size,
                              hipStream_t stream) {
  const float* xr  = (const float*)d_in[0];
  const float* xi  = (const float*)d_in[1];
  const float* Aw  = (const float*)d_in[2];
  const float* PA  = (const float*)d_in[3];
  const float* Wa  = (const float*)d_in[4];
  const float* ba  = (const float*)d_in[5];
  const float* Wb  = (const float*)d_in[6];
  const float* bb  = (const float*)d_in[7];
  const float* Wd  = (const float*)d_in[8];
  const float* bd  = (const float*)d_in[9];
  const float* bnw = (const float*)d_in[10];
  const float* bnb = (const float*)d_in[11];
  float* out = (float*)d_out;
  float* ws = (float*)d_ws;

  // ws layout (floats). bnpart aliases Spart (Spart dead after k2).
  float*    Spart  = ws;                         // 7,680,000 floats
  float*    bnpart = ws;                         // 262,144 floats (alias)
  ushort_t* sfrag  = (ushort_t*)(ws + 7680000);  // 196,608 ushorts
  ushort_t* wfrag  = (ushort_t*)(ws + 7778304);  // 49,152 ushorts
  ushort_t* wab    = (ushort_t*)(ws + 7802880);  // 24,576 ushorts
  float*    coeff  = ws + 7815168;               // 256 floats
  // total ≈ 31.3 MB

  k0_wfrag<<<NS, 256, 0, stream>>>(Wd, Wa, Wb, wfrag, wab);
  k1_spart<<<dim3(64, NN), 256, 0, stream>>>(xr, xi, wab, ba, bb, Spart);
  k2_softmax<<<dim3(NS, NN), 256, 0, stream>>>(Spart, Aw, PA, sfrag);
  k3_y<<<dim3(32, NN), 512, 0, stream>>>(xr, xi, sfrag, wfrag, bd,
                                         (uint32_t*)out, bnpart);
  k4_stats<<<64, 256, 0, stream>>>(bnpart, bnw, bnb, coeff);
  k5_norm<<<6400, 256, 0, stream>>>(xr, xi, coeff, out);
}